// Round 21
// baseline (3604.899 us; speedup 1.0000x reference)
//
#include <hip/hip_runtime.h>
#include <float.h>
#include <limits.h>

// N=131072, K=2048, D=64.
// Verified reference scheme R (rounds 5/7/9-20, absmax 0.0):
//   xsq: numpy NPY_SIMD-128 pairwise (8 vec-accs x 4 lanes + SSE3 hadd tree)
//   esq: scalar pairwise-8; dot: any fp32 order (proven);
//   dist=fl(fl(xsq+esq)-2dot); argmin first-index.
// Round 21: SINGLE-pass screen (pass 2 deleted). Per (lane,row) slot keep
// top-2 (value,index) of the 128 codes it sees, in registers. thr = global
// row min + MARGIN (shfl reduce of slot min1). Collect = register push of
// slot entries <= thr. LOSSLESS: on any slot, margin members are its
// smallest values; a member missing from the slot's top-2 implies
// slot.min2 <= thr, which flags the row -> block-cooperative full exact
// scan (existing fallback). Overflow rows likewise. Expected flags 6-18%
// of rows (margin-member slot collisions), fallback ~0.25us/row.
// Main loop: 16 phases (was 32), half the MFMA / LDS traffic / barriers.
#define D_DIM 64
#define K_CB  2048
#define BM    128
#define NTHREADS 512
#define NWAVES 8
#define KT    128               // codes per staged tile (16 KB)
#define NT    (K_CB / KT)       // 16 tiles
#define MARGIN 2e-3f
#define CAND_CAP 24

typedef __attribute__((ext_vector_type(4))) float f32x4;
typedef __attribute__((ext_vector_type(8))) short s16x8;

__device__ __forceinline__ short f2bf(float f) {   // RN-even fp32->bf16 bits
  unsigned u = __builtin_bit_cast(unsigned, f);
  u += 0x7fffu + ((u >> 16) & 1u);
  return (short)(unsigned short)(u >> 16);
}

__device__ __forceinline__ void gload_lds16(const void* g, void* l) {
  __builtin_amdgcn_global_load_lds(
      (const __attribute__((address_space(1))) unsigned int*)g,
      (__attribute__((address_space(3))) unsigned int*)l, 16, 0, 0);
}

// prep: esq[k] (scalar-8 numpy order, verified) + bf16(-2*e) PRE-SWIZZLED:
//   cbh[k*64 + (d ^ ((k&7)<<3))] = bf16(-2*cb[k][d])
__global__ void __launch_bounds__(256) prep_kernel(const float* __restrict__ cb,
                                                   float* __restrict__ esq,
                                                   unsigned short* __restrict__ cbh) {
#pragma clang fp contract(off)
  int k = blockIdx.x * 256 + threadIdx.x;
  if (k >= K_CB) return;
  const float* row = cb + (size_t)k * D_DIM;
  float r[8];
#pragma unroll
  for (int j = 0; j < 8; ++j) { float v = row[j]; r[j] = v * v; }
#pragma unroll
  for (int i = 1; i < 8; ++i)
#pragma unroll
    for (int j = 0; j < 8; ++j) { float v = row[8 * i + j]; r[j] += v * v; }
  esq[k] = ((r[0] + r[1]) + (r[2] + r[3])) + ((r[4] + r[5]) + (r[6] + r[7]));
  unsigned short* o = cbh + (size_t)k * D_DIM;
  const int sw = (k & 7) << 3;
#pragma unroll
  for (int d = 0; d < D_DIM; ++d)
    o[d ^ sw] = (unsigned short)f2bf(-2.0f * row[d]);
}

__global__ void __launch_bounds__(NTHREADS)
vq_mfma_kernel(const float* __restrict__ x,
               const float* __restrict__ cb,
               const float* __restrict__ esq,
               const unsigned short* __restrict__ cbh,
               float* __restrict__ out) {
#pragma clang fp contract(off)
  // Overlay: prologue = fp32 x tile (32 KB); steady = bbuf[2] (2x16 KB).
  __shared__ __align__(16) char smem[32768];
  __shared__ int   cand_s[BM * CAND_CAP];          // 12 KB
  __shared__ float xsq_s[BM];
  __shared__ int   cnt_s[BM];
  __shared__ int   sus_s[BM];
  __shared__ int   bestk_s[BM];
  __shared__ int   ovf_rows[BM];
  __shared__ int   ovf_cnt;
  __shared__ float fb_v[NWAVES];
  __shared__ int   fb_k[NWAVES];

  const int tid  = threadIdx.x;
  const int lane = tid & 63;
  const int wave = tid >> 6;
  const int row0 = blockIdx.x * BM;

  float4* xs4 = (float4*)smem;                     // prologue view

  // ---- stage x tile (coalesced float4), swizzle float4-col ^= (row>>2)&7 ----
  const float4* xg = (const float4*)(x + (size_t)row0 * D_DIM);
#pragma unroll
  for (int i = 0; i < 4; ++i) {
    int f = tid + i * NTHREADS;                    // 2048 float4
    int row = f >> 4, c4 = f & 15;
    xs4[row * 16 + (c4 ^ ((row >> 2) & 7))] = xg[f];
  }
  if (tid == 0) ovf_cnt = 0;
  if (tid < BM) { cnt_s[tid] = 0; sus_s[tid] = 0; }
  __syncthreads();

  // ---- xsq per row: numpy NPY_SIMD-128 pairwise emulation (verified R5) ----
  if (tid < BM) {
    const int swz = 4 * ((tid >> 2) & 7);
    const float* xr = (const float*)xs4 + tid * 64;
    float s[4];
#pragma unroll
    for (int l = 0; l < 4; ++l) {
      float rj[8];
#pragma unroll
      for (int j = 0; j < 8; ++j) {
        float a = xr[(4 * j + l) ^ swz];
        float b = xr[(32 + 4 * j + l) ^ swz];
        float ta = a * a;
        float tb = b * b;
        rj[j] = ta + tb;
      }
      s[l] = ((rj[0] + rj[1]) + (rj[2] + rj[3])) +
             ((rj[4] + rj[5]) + (rj[6] + rj[7]));
    }
    xsq_s[tid] = (s[0] + s[1]) + (s[2] + s[3]);
  }

  // ---- A fragments: wave owns rows wave*16..wave*16+15 (m89-verified maps:
  //   A: lane row=lane&15, k=(lane>>4)*8+j; B: col=lane&15, same k;
  //   C: col=lane&15, row=(lane>>4)*4+r)
  s16x8 a0, a1;
  {
    const int arow = lane & 15;
    const int kgA = (lane >> 4) * 8;
    const int row = wave * 16 + arow;
    const int sw = (row >> 2) & 7;
    {
      int q0 = kgA >> 2;
      float4 f0 = xs4[row * 16 + (q0 ^ sw)];
      float4 f1 = xs4[row * 16 + ((q0 + 1) ^ sw)];
      a0[0] = f2bf(f0.x); a0[1] = f2bf(f0.y); a0[2] = f2bf(f0.z); a0[3] = f2bf(f0.w);
      a0[4] = f2bf(f1.x); a0[5] = f2bf(f1.y); a0[6] = f2bf(f1.z); a0[7] = f2bf(f1.w);
    }
    {
      int q0 = (32 + kgA) >> 2;
      float4 f0 = xs4[row * 16 + (q0 ^ sw)];
      float4 f1 = xs4[row * 16 + ((q0 + 1) ^ sw)];
      a1[0] = f2bf(f0.x); a1[1] = f2bf(f0.y); a1[2] = f2bf(f0.z); a1[3] = f2bf(f0.w);
      a1[4] = f2bf(f1.x); a1[5] = f2bf(f1.y); a1[6] = f2bf(f1.z); a1[7] = f2bf(f1.w);
    }
  }
  __syncthreads();   // x tile dead; smem becomes bbuf[2][16KB]

  const int ccol = lane & 15;
  const int kg   = (lane >> 4) * 8;
  const int swb  = (ccol & 7) << 3;                // lane-constant
  const int rowbase = wave * 16 + (lane >> 4) * 4;

  // stage tile t (16 KB) into buffer b: 512 threads x 2 x 16B
  auto STAGE = [&](int t, int b) {
    const char* s0 = (const char*)cbh + (size_t)t * 16384 + wave * 2048 + lane * 16;
    char* d0 = smem + b * 16384 + wave * 2048;
    gload_lds16(s0, d0);
    gload_lds16(s0 + 1024, d0 + 1024);
  };

  // ========== SINGLE screen pass: per-slot top-2 (value,index) ==========
  float m1[4], m2[4];
  int   i1[4], i2[4];
#pragma unroll
  for (int r = 0; r < 4; ++r) {
    m1[r] = FLT_MAX; m2[r] = FLT_MAX; i1[r] = INT_MAX; i2[r] = INT_MAX;
  }

  STAGE(0, 0);
  __syncthreads();
  for (int t = 0; t < NT; ++t) {
    if (t + 1 < NT) STAGE(t + 1, (t + 1) & 1);
    const unsigned short* B = (const unsigned short*)(smem + (t & 1) * 16384);
    const int kbase = t * KT + ccol;
#pragma unroll
    for (int st = 0; st < 8; ++st) {
      const unsigned short* bp = B + (st * 16 + ccol) * 64;
      s16x8 b0 = *(const s16x8*)(bp + (kg ^ swb));
      s16x8 b1 = *(const s16x8*)(bp + ((32 + kg) ^ swb));
      f32x4 acc = {0.f, 0.f, 0.f, 0.f};
      acc = __builtin_amdgcn_mfma_f32_16x16x32_bf16(a0, b0, acc, 0, 0, 0);
      acc = __builtin_amdgcn_mfma_f32_16x16x32_bf16(a1, b1, acc, 0, 0, 0);
      const int kk = kbase + st * 16;
#pragma unroll
      for (int r = 0; r < 4; ++r) {
        float v = acc[r];
        bool lt1 = v < m1[r];
        bool lt2 = v < m2[r];
        // top-2 update, branchless
        float nm2 = lt1 ? m1[r] : (lt2 ? v : m2[r]);
        int   ni2 = lt1 ? i1[r] : (lt2 ? kk : i2[r]);
        m2[r] = nm2; i2[r] = ni2;
        m1[r] = lt1 ? v : m1[r];
        i1[r] = lt1 ? kk : i1[r];
      }
    }
    __syncthreads();
  }

  // per-row global min across the 16 covering lanes -> thr (wave-local)
  float thr[4];
#pragma unroll
  for (int r = 0; r < 4; ++r) {
    float v = m1[r];
    v = fminf(v, __shfl_xor(v, 1));
    v = fminf(v, __shfl_xor(v, 2));
    v = fminf(v, __shfl_xor(v, 4));
    v = fminf(v, __shfl_xor(v, 8));
    thr[r] = v + MARGIN;
  }

  // ====== collect from registers (no MFMA replay) ======
#pragma unroll
  for (int r = 0; r < 4; ++r) {
    int row = rowbase + r;
    if (m1[r] <= thr[r]) {
      int pos = atomicAdd(&cnt_s[row], 1);
      if (pos < CAND_CAP) cand_s[row * CAND_CAP + pos] = i1[r];
    }
    if (m2[r] <= thr[r]) {
      // slot had >=2 margin members -> possible hidden 3rd: flag row
      sus_s[row] = 1;
      int pos = atomicAdd(&cnt_s[row], 1);
      if (pos < CAND_CAP) cand_s[row * CAND_CAP + pos] = i2[r];
    }
  }
  __syncthreads();

  // ====== exact rescore (R-scheme), lex-(dist,k); 4 threads per row.
  //        x read from GLOBAL (linear d-order: verified-passing order). ======
  {
    const int row = tid >> 2, slot = tid & 3;
    const int cnt = cnt_s[row];
    if (cnt <= CAND_CAP && !sus_s[row]) {
      const float* xr = x + (size_t)(row0 + row) * D_DIM;
      const float xq = xsq_s[row];
      float bv = FLT_MAX; int bk = INT_MAX;
      for (int i = slot; i < cnt; i += 4) {
        int k = cand_s[row * CAND_CAP + i];
        const float* er = cb + (size_t)k * D_DIM;
        float a = 0.f;
#pragma unroll 8
        for (int d = 0; d < D_DIM; ++d) a = fmaf(xr[d], er[d], a);
        float dist = (xq + esq[k]) - 2.0f * a;
        if (dist < bv || (dist == bv && k < bk)) { bv = dist; bk = k; }
      }
#pragma unroll
      for (int m = 1; m <= 2; m <<= 1) {
        float ov = __shfl_xor(bv, m); int ok = __shfl_xor(bk, m);
        if (ov < bv || (ov == bv && ok < bk)) { bv = ov; bk = ok; }
      }
      if (slot == 0) bestk_s[row] = bk;
    }
  }
  if (tid < BM && (cnt_s[tid] > CAND_CAP || sus_s[tid])) {
    int p = atomicAdd(&ovf_cnt, 1);
    ovf_rows[p] = tid;
  }
  __syncthreads();

  // ====== lossless fallback: block-cooperative full exact scan ======
  {
    const int novf = ovf_cnt;
    for (int i = 0; i < novf; ++i) {
      const int row = ovf_rows[i];
      const float* xr = x + (size_t)(row0 + row) * D_DIM;
      const float xq = xsq_s[row];
      float bv = FLT_MAX; int bk = INT_MAX;
      for (int k = tid; k < K_CB; k += NTHREADS) {
        const float* er = cb + (size_t)k * D_DIM;
        float a = 0.f;
#pragma unroll 8
        for (int d = 0; d < D_DIM; ++d) a = fmaf(xr[d], er[d], a);
        float dist = (xq + esq[k]) - 2.0f * a;
        if (dist < bv || (dist == bv && k < bk)) { bv = dist; bk = k; }
      }
#pragma unroll
      for (int m = 1; m <= 32; m <<= 1) {
        float ov = __shfl_xor(bv, m); int ok = __shfl_xor(bk, m);
        if (ov < bv || (ov == bv && ok < bk)) { bv = ov; bk = ok; }
      }
      if (lane == 0) { fb_v[wave] = bv; fb_k[wave] = bk; }
      __syncthreads();
      if (tid == 0) {
        float BV = fb_v[0]; int BK = fb_k[0];
#pragma unroll
        for (int w = 1; w < NWAVES; ++w)
          if (fb_v[w] < BV || (fb_v[w] == BV && fb_k[w] < BK)) { BV = fb_v[w]; BK = fb_k[w]; }
        bestk_s[row] = BK;
      }
      __syncthreads();
    }
  }
  __syncthreads();

  // ---- gather: out[row] = codebook[bestk[row]], coalesced float4 ----
  const float4* cb4 = (const float4*)cb;
  float4* out4 = (float4*)out + (size_t)row0 * 16;
#pragma unroll
  for (int i = 0; i < 4; ++i) {
    int f = tid + i * NTHREADS;
    int row = f >> 4, c4 = f & 15;
    out4[f] = cb4[(size_t)bestk_s[row] * 16 + c4];
  }
}

extern "C" void kernel_launch(void* const* d_in, const int* in_sizes, int n_in,
                              void* d_out, int out_size, void* d_ws, size_t ws_size,
                              hipStream_t stream) {
  const float* x  = (const float*)d_in[0];   // [N, 64] fp32
  const float* cb = (const float*)d_in[1];   // [2048, 64] fp32
  float* out = (float*)d_out;                // [N, 64] fp32
  float* esq = (float*)d_ws;                 // [2048] fp32
  unsigned short* cbh = (unsigned short*)d_ws + 4096;  // swizzled bf16(-2e), 256 KB

  const int N = in_sizes[0] / D_DIM;         // 131072

  prep_kernel<<<(K_CB + 255) / 256, 256, 0, stream>>>(cb, esq, cbh);
  vq_mfma_kernel<<<N / BM, NTHREADS, 0, stream>>>(x, cb, esq, cbh, out);
}

// Round 22
// 187.578 us; speedup vs baseline: 19.2181x; 19.2181x over previous
//
#include <hip/hip_runtime.h>
#include <float.h>
#include <limits.h>

// N=131072, K=2048, D=64.
// Verified reference scheme R (rounds 5/7/9-20, absmax 0.0):
//   xsq: numpy NPY_SIMD-128 pairwise (8 vec-accs x 4 lanes + SSE3 hadd tree)
//   esq: scalar pairwise-8; dot: any fp32 order (proven);
//   dist=fl(fl(xsq+esq)-2dot); argmin first-index.
// Round 22 = R20 verbatim (best-known-good, 187us). R21's single-pass
// top-2 regressed 18x: the m2<=thr flag fired on ~25% of rows, flooding
// the (lossless but per-row-expensive) full-scan fallback. Conclusion of
// the structural search (R7-R21): the 2-pass staged screen at KT=128 /
// BM=128 / 512 threads is the plateau optimum (~190us, latency-bound:
// MfmaUtil 14%, VALUBusy 18%, HBM 3.6%); every other lever (work/phase x4,
// blocks/CU x2, counted vmcnt, reg-prefetch, reg-resident B, single-pass)
// measured neutral-to-negative.
#define D_DIM 64
#define K_CB  2048
#define BM    128
#define NTHREADS 512
#define NWAVES 8
#define KT    128               // codes per staged tile (16 KB)
#define NT    (K_CB / KT)       // 16 tiles
#define MARGIN 2e-3f
#define CAND_CAP 24

typedef __attribute__((ext_vector_type(4))) float f32x4;
typedef __attribute__((ext_vector_type(8))) short s16x8;

__device__ __forceinline__ short f2bf(float f) {   // RN-even fp32->bf16 bits
  unsigned u = __builtin_bit_cast(unsigned, f);
  u += 0x7fffu + ((u >> 16) & 1u);
  return (short)(unsigned short)(u >> 16);
}

__device__ __forceinline__ void gload_lds16(const void* g, void* l) {
  __builtin_amdgcn_global_load_lds(
      (const __attribute__((address_space(1))) unsigned int*)g,
      (__attribute__((address_space(3))) unsigned int*)l, 16, 0, 0);
}

// prep: esq[k] (scalar-8 numpy order, verified) + bf16(-2*e) PRE-SWIZZLED:
//   cbh[k*64 + (d ^ ((k&7)<<3))] = bf16(-2*cb[k][d])
__global__ void __launch_bounds__(256) prep_kernel(const float* __restrict__ cb,
                                                   float* __restrict__ esq,
                                                   unsigned short* __restrict__ cbh) {
#pragma clang fp contract(off)
  int k = blockIdx.x * 256 + threadIdx.x;
  if (k >= K_CB) return;
  const float* row = cb + (size_t)k * D_DIM;
  float r[8];
#pragma unroll
  for (int j = 0; j < 8; ++j) { float v = row[j]; r[j] = v * v; }
#pragma unroll
  for (int i = 1; i < 8; ++i)
#pragma unroll
    for (int j = 0; j < 8; ++j) { float v = row[8 * i + j]; r[j] += v * v; }
  esq[k] = ((r[0] + r[1]) + (r[2] + r[3])) + ((r[4] + r[5]) + (r[6] + r[7]));
  unsigned short* o = cbh + (size_t)k * D_DIM;
  const int sw = (k & 7) << 3;
#pragma unroll
  for (int d = 0; d < D_DIM; ++d)
    o[d ^ sw] = (unsigned short)f2bf(-2.0f * row[d]);
}

__global__ void __launch_bounds__(NTHREADS)
vq_mfma_kernel(const float* __restrict__ x,
               const float* __restrict__ cb,
               const float* __restrict__ esq,
               const unsigned short* __restrict__ cbh,
               float* __restrict__ out) {
#pragma clang fp contract(off)
  // Overlay: prologue = fp32 x tile (32 KB); steady = bbuf[2] (2x16 KB).
  __shared__ __align__(16) char smem[32768];
  __shared__ int   cand_s[BM * CAND_CAP];          // 12 KB (not overlaid)
  __shared__ float xsq_s[BM];
  __shared__ float rowthr_s[BM];
  __shared__ int   cnt_s[BM];
  __shared__ int   bestk_s[BM];
  __shared__ int   ovf_rows[BM];
  __shared__ int   ovf_cnt;
  __shared__ float fb_v[NWAVES];
  __shared__ int   fb_k[NWAVES];

  const int tid  = threadIdx.x;
  const int lane = tid & 63;
  const int wave = tid >> 6;
  const int row0 = blockIdx.x * BM;

  float4* xs4 = (float4*)smem;                     // prologue view

  // ---- stage x tile (coalesced float4), swizzle float4-col ^= (row>>2)&7 ----
  const float4* xg = (const float4*)(x + (size_t)row0 * D_DIM);
#pragma unroll
  for (int i = 0; i < 4; ++i) {
    int f = tid + i * NTHREADS;                    // 2048 float4
    int row = f >> 4, c4 = f & 15;
    xs4[row * 16 + (c4 ^ ((row >> 2) & 7))] = xg[f];
  }
  if (tid == 0) ovf_cnt = 0;
  if (tid < BM) cnt_s[tid] = 0;
  __syncthreads();

  // ---- xsq per row: numpy NPY_SIMD-128 pairwise emulation (verified R5) ----
  if (tid < BM) {
    const int swz = 4 * ((tid >> 2) & 7);
    const float* xr = (const float*)xs4 + tid * 64;
    float s[4];
#pragma unroll
    for (int l = 0; l < 4; ++l) {
      float rj[8];
#pragma unroll
      for (int j = 0; j < 8; ++j) {
        float a = xr[(4 * j + l) ^ swz];
        float b = xr[(32 + 4 * j + l) ^ swz];
        float ta = a * a;
        float tb = b * b;
        rj[j] = ta + tb;
      }
      s[l] = ((rj[0] + rj[1]) + (rj[2] + rj[3])) +
             ((rj[4] + rj[5]) + (rj[6] + rj[7]));
    }
    xsq_s[tid] = (s[0] + s[1]) + (s[2] + s[3]);
  }

  // ---- A fragments: wave owns rows wave*16..wave*16+15 (m89-verified maps:
  //   A: lane row=lane&15, k=(lane>>4)*8+j; B: col=lane&15, same k;
  //   C: col=lane&15, row=(lane>>4)*4+r)
  s16x8 a0, a1;
  {
    const int arow = lane & 15;
    const int kgA = (lane >> 4) * 8;
    const int row = wave * 16 + arow;
    const int sw = (row >> 2) & 7;
    {
      int q0 = kgA >> 2;
      float4 f0 = xs4[row * 16 + (q0 ^ sw)];
      float4 f1 = xs4[row * 16 + ((q0 + 1) ^ sw)];
      a0[0] = f2bf(f0.x); a0[1] = f2bf(f0.y); a0[2] = f2bf(f0.z); a0[3] = f2bf(f0.w);
      a0[4] = f2bf(f1.x); a0[5] = f2bf(f1.y); a0[6] = f2bf(f1.z); a0[7] = f2bf(f1.w);
    }
    {
      int q0 = (32 + kgA) >> 2;
      float4 f0 = xs4[row * 16 + (q0 ^ sw)];
      float4 f1 = xs4[row * 16 + ((q0 + 1) ^ sw)];
      a1[0] = f2bf(f0.x); a1[1] = f2bf(f0.y); a1[2] = f2bf(f0.z); a1[3] = f2bf(f0.w);
      a1[4] = f2bf(f1.x); a1[5] = f2bf(f1.y); a1[6] = f2bf(f1.z); a1[7] = f2bf(f1.w);
    }
  }
  __syncthreads();   // x tile dead; smem becomes bbuf[2][16KB]

  const int ccol = lane & 15;
  const int kg   = (lane >> 4) * 8;
  const int swb  = (ccol & 7) << 3;                // lane-constant
  const int rowbase = wave * 16 + (lane >> 4) * 4;

  // stage tile t (16 KB) into buffer b: 512 threads x 2 x 16B
  auto STAGE = [&](int t, int b) {
    const char* s0 = (const char*)cbh + (size_t)t * 16384 + wave * 2048 + lane * 16;
    char* d0 = smem + b * 16384 + wave * 2048;
    gload_lds16(s0, d0);
    gload_lds16(s0 + 1024, d0 + 1024);
  };

  // ================= pass 1: per-row screen min =================
  float minv[4];
  minv[0] = minv[1] = minv[2] = minv[3] = FLT_MAX;

  STAGE(0, 0);
  __syncthreads();
  for (int t = 0; t < NT; ++t) {
    if (t + 1 < NT) STAGE(t + 1, (t + 1) & 1);
    const unsigned short* B = (const unsigned short*)(smem + (t & 1) * 16384);
#pragma unroll
    for (int st = 0; st < 8; ++st) {
      const unsigned short* bp = B + (st * 16 + ccol) * 64;
      s16x8 b0 = *(const s16x8*)(bp + (kg ^ swb));
      s16x8 b1 = *(const s16x8*)(bp + ((32 + kg) ^ swb));
      f32x4 acc = {0.f, 0.f, 0.f, 0.f};
      acc = __builtin_amdgcn_mfma_f32_16x16x32_bf16(a0, b0, acc, 0, 0, 0);
      acc = __builtin_amdgcn_mfma_f32_16x16x32_bf16(a1, b1, acc, 0, 0, 0);
#pragma unroll
      for (int r = 0; r < 4; ++r) minv[r] = fminf(minv[r], acc[r]);
    }
    __syncthreads();
  }

  // per-row min across the 16 covering lanes (rows are wave-private)
#pragma unroll
  for (int r = 0; r < 4; ++r) {
    float v = minv[r];
#pragma unroll
    for (int m = 1; m <= 8; m <<= 1) v = fminf(v, __shfl_xor(v, m));
    minv[r] = v;
  }
  if ((lane & 15) == 0) {
#pragma unroll
    for (int r = 0; r < 4; ++r)
      rowthr_s[rowbase + r] = minv[r] + MARGIN;
  }
  __syncthreads();

  float thr[4];
#pragma unroll
  for (int r = 0; r < 4; ++r)
    thr[r] = rowthr_s[rowbase + r];

  // ====== pass 2: recompute (bit-identical), collect candidates ======
  STAGE(0, 0);
  __syncthreads();
  for (int t = 0; t < NT; ++t) {
    if (t + 1 < NT) STAGE(t + 1, (t + 1) & 1);
    const unsigned short* B = (const unsigned short*)(smem + (t & 1) * 16384);
#pragma unroll
    for (int st = 0; st < 8; ++st) {
      const unsigned short* bp = B + (st * 16 + ccol) * 64;
      s16x8 b0 = *(const s16x8*)(bp + (kg ^ swb));
      s16x8 b1 = *(const s16x8*)(bp + ((32 + kg) ^ swb));
      f32x4 acc = {0.f, 0.f, 0.f, 0.f};
      acc = __builtin_amdgcn_mfma_f32_16x16x32_bf16(a0, b0, acc, 0, 0, 0);
      acc = __builtin_amdgcn_mfma_f32_16x16x32_bf16(a1, b1, acc, 0, 0, 0);
#pragma unroll
      for (int r = 0; r < 4; ++r) {
        if (acc[r] <= thr[r]) {
          int row = rowbase + r;
          int pos = atomicAdd(&cnt_s[row], 1);
          if (pos < CAND_CAP) cand_s[row * CAND_CAP + pos] = t * KT + st * 16 + ccol;
        }
      }
    }
    __syncthreads();
  }

  // ====== exact rescore (R-scheme), lex-(dist,k); 4 threads per row.
  //        x read from GLOBAL (linear d-order: verified-passing order). ======
  {
    const int row = tid >> 2, slot = tid & 3;
    const int cnt = cnt_s[row];
    if (cnt <= CAND_CAP) {
      const float* xr = x + (size_t)(row0 + row) * D_DIM;
      const float xq = xsq_s[row];
      float bv = FLT_MAX; int bk = INT_MAX;
      for (int i = slot; i < cnt; i += 4) {
        int k = cand_s[row * CAND_CAP + i];
        const float* er = cb + (size_t)k * D_DIM;
        float a = 0.f;
#pragma unroll 8
        for (int d = 0; d < D_DIM; ++d) a = fmaf(xr[d], er[d], a);
        float dist = (xq + esq[k]) - 2.0f * a;
        if (dist < bv || (dist == bv && k < bk)) { bv = dist; bk = k; }
      }
#pragma unroll
      for (int m = 1; m <= 2; m <<= 1) {
        float ov = __shfl_xor(bv, m); int ok = __shfl_xor(bk, m);
        if (ov < bv || (ov == bv && ok < bk)) { bv = ov; bk = ok; }
      }
      if (slot == 0) bestk_s[row] = bk;
    }
  }
  if (tid < BM && cnt_s[tid] > CAND_CAP) {
    int p = atomicAdd(&ovf_cnt, 1);
    ovf_rows[p] = tid;
  }
  __syncthreads();

  // ====== lossless overflow fallback: block-cooperative full scan ======
  {
    const int novf = ovf_cnt;
    for (int i = 0; i < novf; ++i) {
      const int row = ovf_rows[i];
      const float* xr = x + (size_t)(row0 + row) * D_DIM;
      const float xq = xsq_s[row];
      float bv = FLT_MAX; int bk = INT_MAX;
      for (int k = tid; k < K_CB; k += NTHREADS) {
        const float* er = cb + (size_t)k * D_DIM;
        float a = 0.f;
#pragma unroll 8
        for (int d = 0; d < D_DIM; ++d) a = fmaf(xr[d], er[d], a);
        float dist = (xq + esq[k]) - 2.0f * a;
        if (dist < bv || (dist == bv && k < bk)) { bv = dist; bk = k; }
      }
#pragma unroll
      for (int m = 1; m <= 32; m <<= 1) {
        float ov = __shfl_xor(bv, m); int ok = __shfl_xor(bk, m);
        if (ov < bv || (ov == bv && ok < bk)) { bv = ov; bk = ok; }
      }
      if (lane == 0) { fb_v[wave] = bv; fb_k[wave] = bk; }
      __syncthreads();
      if (tid == 0) {
        float BV = fb_v[0]; int BK = fb_k[0];
#pragma unroll
        for (int w = 1; w < NWAVES; ++w)
          if (fb_v[w] < BV || (fb_v[w] == BV && fb_k[w] < BK)) { BV = fb_v[w]; BK = fb_k[w]; }
        bestk_s[row] = BK;
      }
      __syncthreads();
    }
  }
  __syncthreads();

  // ---- gather: out[row] = codebook[bestk[row]], coalesced float4 ----
  const float4* cb4 = (const float4*)cb;
  float4* out4 = (float4*)out + (size_t)row0 * 16;
#pragma unroll
  for (int i = 0; i < 4; ++i) {
    int f = tid + i * NTHREADS;
    int row = f >> 4, c4 = f & 15;
    out4[f] = cb4[(size_t)bestk_s[row] * 16 + c4];
  }
}

extern "C" void kernel_launch(void* const* d_in, const int* in_sizes, int n_in,
                              void* d_out, int out_size, void* d_ws, size_t ws_size,
                              hipStream_t stream) {
  const float* x  = (const float*)d_in[0];   // [N, 64] fp32
  const float* cb = (const float*)d_in[1];   // [2048, 64] fp32
  float* out = (float*)d_out;                // [N, 64] fp32
  float* esq = (float*)d_ws;                 // [2048] fp32
  unsigned short* cbh = (unsigned short*)d_ws + 4096;  // swizzled bf16(-2e), 256 KB

  const int N = in_sizes[0] / D_DIM;         // 131072

  prep_kernel<<<(K_CB + 255) / 256, 256, 0, stream>>>(cb, esq, cbh);
  vq_mfma_kernel<<<N / BM, NTHREADS, 0, stream>>>(x, cb, esq, cbh, out);
}

// Round 23
// 181.492 us; speedup vs baseline: 19.8625x; 1.0335x over previous
//
#include <hip/hip_runtime.h>
#include <float.h>
#include <limits.h>

// N=131072, K=2048, D=64.
// Verified reference scheme R (rounds 5/7/9-22, absmax 0.0):
//   xsq: numpy NPY_SIMD-128 pairwise (8 vec-accs x 4 lanes + SSE3 hadd tree)
//   esq: scalar pairwise-8; dot: any fp32 order (proven);
//   dist=fl(fl(xsq+esq)-2dot); argmin first-index.
// Round 23 = R22 with KT 128->256 (NT=8): the phase-count lever was the
// only structural knob with positive measured slope (64->32 phases: +5%,
// R19->R20). 8 phases/pass (16 total), 32 KB staged per phase into a 64 KB
// double-buffer (x-tile overlays its first half during prologue), 16
// subtiles (32 MFMA/wave) per phase. Static LDS ~80.4 KB -> 2 blocks/CU
// (within 81.9 KB bound). Algorithm byte-identical to R20/R22: folded -2e
// bf16 MFMA screen, 2-pass margin collect, exact R rescore (x from
// global), lossless block-cooperative overflow fallback.
#define D_DIM 64
#define K_CB  2048
#define BM    128
#define NTHREADS 512
#define NWAVES 8
#define KT    256               // codes per staged tile (32 KB)
#define NT    (K_CB / KT)       // 8 tiles
#define MARGIN 2e-3f
#define CAND_CAP 24

typedef __attribute__((ext_vector_type(4))) float f32x4;
typedef __attribute__((ext_vector_type(8))) short s16x8;

__device__ __forceinline__ short f2bf(float f) {   // RN-even fp32->bf16 bits
  unsigned u = __builtin_bit_cast(unsigned, f);
  u += 0x7fffu + ((u >> 16) & 1u);
  return (short)(unsigned short)(u >> 16);
}

__device__ __forceinline__ void gload_lds16(const void* g, void* l) {
  __builtin_amdgcn_global_load_lds(
      (const __attribute__((address_space(1))) unsigned int*)g,
      (__attribute__((address_space(3))) unsigned int*)l, 16, 0, 0);
}

// prep: esq[k] (scalar-8 numpy order, verified) + bf16(-2*e) PRE-SWIZZLED:
//   cbh[k*64 + (d ^ ((k&7)<<3))] = bf16(-2*cb[k][d])
__global__ void __launch_bounds__(256) prep_kernel(const float* __restrict__ cb,
                                                   float* __restrict__ esq,
                                                   unsigned short* __restrict__ cbh) {
#pragma clang fp contract(off)
  int k = blockIdx.x * 256 + threadIdx.x;
  if (k >= K_CB) return;
  const float* row = cb + (size_t)k * D_DIM;
  float r[8];
#pragma unroll
  for (int j = 0; j < 8; ++j) { float v = row[j]; r[j] = v * v; }
#pragma unroll
  for (int i = 1; i < 8; ++i)
#pragma unroll
    for (int j = 0; j < 8; ++j) { float v = row[8 * i + j]; r[j] += v * v; }
  esq[k] = ((r[0] + r[1]) + (r[2] + r[3])) + ((r[4] + r[5]) + (r[6] + r[7]));
  unsigned short* o = cbh + (size_t)k * D_DIM;
  const int sw = (k & 7) << 3;
#pragma unroll
  for (int d = 0; d < D_DIM; ++d)
    o[d ^ sw] = (unsigned short)f2bf(-2.0f * row[d]);
}

__global__ void __launch_bounds__(NTHREADS)
vq_mfma_kernel(const float* __restrict__ x,
               const float* __restrict__ cb,
               const float* __restrict__ esq,
               const unsigned short* __restrict__ cbh,
               float* __restrict__ out) {
#pragma clang fp contract(off)
  // 64 KB region: prologue = fp32 x tile (32 KB, first half);
  // steady = bbuf[2] (2 x 32 KB double-buffer).
  __shared__ __align__(16) char smem[65536];
  __shared__ int   cand_s[BM * CAND_CAP];          // 12 KB
  __shared__ float xsq_s[BM];
  __shared__ float rowthr_s[BM];
  __shared__ int   cnt_s[BM];
  __shared__ int   bestk_s[BM];
  __shared__ int   ovf_rows[BM];
  __shared__ int   ovf_cnt;
  __shared__ float fb_v[NWAVES];
  __shared__ int   fb_k[NWAVES];

  const int tid  = threadIdx.x;
  const int lane = tid & 63;
  const int wave = tid >> 6;
  const int row0 = blockIdx.x * BM;

  float4* xs4 = (float4*)smem;                     // prologue view

  // ---- stage x tile (coalesced float4), swizzle float4-col ^= (row>>2)&7 ----
  const float4* xg = (const float4*)(x + (size_t)row0 * D_DIM);
#pragma unroll
  for (int i = 0; i < 4; ++i) {
    int f = tid + i * NTHREADS;                    // 2048 float4
    int row = f >> 4, c4 = f & 15;
    xs4[row * 16 + (c4 ^ ((row >> 2) & 7))] = xg[f];
  }
  if (tid == 0) ovf_cnt = 0;
  if (tid < BM) cnt_s[tid] = 0;
  __syncthreads();

  // ---- xsq per row: numpy NPY_SIMD-128 pairwise emulation (verified R5) ----
  if (tid < BM) {
    const int swz = 4 * ((tid >> 2) & 7);
    const float* xr = (const float*)xs4 + tid * 64;
    float s[4];
#pragma unroll
    for (int l = 0; l < 4; ++l) {
      float rj[8];
#pragma unroll
      for (int j = 0; j < 8; ++j) {
        float a = xr[(4 * j + l) ^ swz];
        float b = xr[(32 + 4 * j + l) ^ swz];
        float ta = a * a;
        float tb = b * b;
        rj[j] = ta + tb;
      }
      s[l] = ((rj[0] + rj[1]) + (rj[2] + rj[3])) +
             ((rj[4] + rj[5]) + (rj[6] + rj[7]));
    }
    xsq_s[tid] = (s[0] + s[1]) + (s[2] + s[3]);
  }

  // ---- A fragments: wave owns rows wave*16..wave*16+15 (m89-verified maps:
  //   A: lane row=lane&15, k=(lane>>4)*8+j; B: col=lane&15, same k;
  //   C: col=lane&15, row=(lane>>4)*4+r)
  s16x8 a0, a1;
  {
    const int arow = lane & 15;
    const int kgA = (lane >> 4) * 8;
    const int row = wave * 16 + arow;
    const int sw = (row >> 2) & 7;
    {
      int q0 = kgA >> 2;
      float4 f0 = xs4[row * 16 + (q0 ^ sw)];
      float4 f1 = xs4[row * 16 + ((q0 + 1) ^ sw)];
      a0[0] = f2bf(f0.x); a0[1] = f2bf(f0.y); a0[2] = f2bf(f0.z); a0[3] = f2bf(f0.w);
      a0[4] = f2bf(f1.x); a0[5] = f2bf(f1.y); a0[6] = f2bf(f1.z); a0[7] = f2bf(f1.w);
    }
    {
      int q0 = (32 + kgA) >> 2;
      float4 f0 = xs4[row * 16 + (q0 ^ sw)];
      float4 f1 = xs4[row * 16 + ((q0 + 1) ^ sw)];
      a1[0] = f2bf(f0.x); a1[1] = f2bf(f0.y); a1[2] = f2bf(f0.z); a1[3] = f2bf(f0.w);
      a1[4] = f2bf(f1.x); a1[5] = f2bf(f1.y); a1[6] = f2bf(f1.z); a1[7] = f2bf(f1.w);
    }
  }
  __syncthreads();   // x tile dead; smem becomes bbuf[2][32KB]

  const int ccol = lane & 15;
  const int kg   = (lane >> 4) * 8;
  const int swb  = (ccol & 7) << 3;                // lane-constant
  const int rowbase = wave * 16 + (lane >> 4) * 4;

  // stage tile t (32 KB) into buffer b: 512 threads x 4 x 16B
  auto STAGE = [&](int t, int b) {
    const char* s0 = (const char*)cbh + (size_t)t * 32768 + wave * 4096 + lane * 16;
    char* d0 = smem + b * 32768 + wave * 4096;
    gload_lds16(s0, d0);
    gload_lds16(s0 + 1024, d0 + 1024);
    gload_lds16(s0 + 2048, d0 + 2048);
    gload_lds16(s0 + 3072, d0 + 3072);
  };

  // ================= pass 1: per-row screen min =================
  float minv[4];
  minv[0] = minv[1] = minv[2] = minv[3] = FLT_MAX;

  STAGE(0, 0);
  __syncthreads();
  for (int t = 0; t < NT; ++t) {
    if (t + 1 < NT) STAGE(t + 1, (t + 1) & 1);
    const unsigned short* B = (const unsigned short*)(smem + (t & 1) * 32768);
#pragma unroll
    for (int st = 0; st < 16; ++st) {
      const unsigned short* bp = B + (st * 16 + ccol) * 64;
      s16x8 b0 = *(const s16x8*)(bp + (kg ^ swb));
      s16x8 b1 = *(const s16x8*)(bp + ((32 + kg) ^ swb));
      f32x4 acc = {0.f, 0.f, 0.f, 0.f};
      acc = __builtin_amdgcn_mfma_f32_16x16x32_bf16(a0, b0, acc, 0, 0, 0);
      acc = __builtin_amdgcn_mfma_f32_16x16x32_bf16(a1, b1, acc, 0, 0, 0);
#pragma unroll
      for (int r = 0; r < 4; ++r) minv[r] = fminf(minv[r], acc[r]);
    }
    __syncthreads();
  }

  // per-row min across the 16 covering lanes (rows are wave-private)
#pragma unroll
  for (int r = 0; r < 4; ++r) {
    float v = minv[r];
#pragma unroll
    for (int m = 1; m <= 8; m <<= 1) v = fminf(v, __shfl_xor(v, m));
    minv[r] = v;
  }
  if ((lane & 15) == 0) {
#pragma unroll
    for (int r = 0; r < 4; ++r)
      rowthr_s[rowbase + r] = minv[r] + MARGIN;
  }
  __syncthreads();

  float thr[4];
#pragma unroll
  for (int r = 0; r < 4; ++r)
    thr[r] = rowthr_s[rowbase + r];

  // ====== pass 2: recompute (bit-identical), collect candidates ======
  STAGE(0, 0);
  __syncthreads();
  for (int t = 0; t < NT; ++t) {
    if (t + 1 < NT) STAGE(t + 1, (t + 1) & 1);
    const unsigned short* B = (const unsigned short*)(smem + (t & 1) * 32768);
#pragma unroll
    for (int st = 0; st < 16; ++st) {
      const unsigned short* bp = B + (st * 16 + ccol) * 64;
      s16x8 b0 = *(const s16x8*)(bp + (kg ^ swb));
      s16x8 b1 = *(const s16x8*)(bp + ((32 + kg) ^ swb));
      f32x4 acc = {0.f, 0.f, 0.f, 0.f};
      acc = __builtin_amdgcn_mfma_f32_16x16x32_bf16(a0, b0, acc, 0, 0, 0);
      acc = __builtin_amdgcn_mfma_f32_16x16x32_bf16(a1, b1, acc, 0, 0, 0);
#pragma unroll
      for (int r = 0; r < 4; ++r) {
        if (acc[r] <= thr[r]) {
          int row = rowbase + r;
          int pos = atomicAdd(&cnt_s[row], 1);
          if (pos < CAND_CAP) cand_s[row * CAND_CAP + pos] = t * KT + st * 16 + ccol;
        }
      }
    }
    __syncthreads();
  }

  // ====== exact rescore (R-scheme), lex-(dist,k); 4 threads per row.
  //        x read from GLOBAL (linear d-order: verified-passing order). ======
  {
    const int row = tid >> 2, slot = tid & 3;
    const int cnt = cnt_s[row];
    if (cnt <= CAND_CAP) {
      const float* xr = x + (size_t)(row0 + row) * D_DIM;
      const float xq = xsq_s[row];
      float bv = FLT_MAX; int bk = INT_MAX;
      for (int i = slot; i < cnt; i += 4) {
        int k = cand_s[row * CAND_CAP + i];
        const float* er = cb + (size_t)k * D_DIM;
        float a = 0.f;
#pragma unroll 8
        for (int d = 0; d < D_DIM; ++d) a = fmaf(xr[d], er[d], a);
        float dist = (xq + esq[k]) - 2.0f * a;
        if (dist < bv || (dist == bv && k < bk)) { bv = dist; bk = k; }
      }
#pragma unroll
      for (int m = 1; m <= 2; m <<= 1) {
        float ov = __shfl_xor(bv, m); int ok = __shfl_xor(bk, m);
        if (ov < bv || (ov == bv && ok < bk)) { bv = ov; bk = ok; }
      }
      if (slot == 0) bestk_s[row] = bk;
    }
  }
  if (tid < BM && cnt_s[tid] > CAND_CAP) {
    int p = atomicAdd(&ovf_cnt, 1);
    ovf_rows[p] = tid;
  }
  __syncthreads();

  // ====== lossless overflow fallback: block-cooperative full scan ======
  {
    const int novf = ovf_cnt;
    for (int i = 0; i < novf; ++i) {
      const int row = ovf_rows[i];
      const float* xr = x + (size_t)(row0 + row) * D_DIM;
      const float xq = xsq_s[row];
      float bv = FLT_MAX; int bk = INT_MAX;
      for (int k = tid; k < K_CB; k += NTHREADS) {
        const float* er = cb + (size_t)k * D_DIM;
        float a = 0.f;
#pragma unroll 8
        for (int d = 0; d < D_DIM; ++d) a = fmaf(xr[d], er[d], a);
        float dist = (xq + esq[k]) - 2.0f * a;
        if (dist < bv || (dist == bv && k < bk)) { bv = dist; bk = k; }
      }
#pragma unroll
      for (int m = 1; m <= 32; m <<= 1) {
        float ov = __shfl_xor(bv, m); int ok = __shfl_xor(bk, m);
        if (ov < bv || (ov == bv && ok < bk)) { bv = ov; bk = ok; }
      }
      if (lane == 0) { fb_v[wave] = bv; fb_k[wave] = bk; }
      __syncthreads();
      if (tid == 0) {
        float BV = fb_v[0]; int BK = fb_k[0];
#pragma unroll
        for (int w = 1; w < NWAVES; ++w)
          if (fb_v[w] < BV || (fb_v[w] == BV && fb_k[w] < BK)) { BV = fb_v[w]; BK = fb_k[w]; }
        bestk_s[row] = BK;
      }
      __syncthreads();
    }
  }
  __syncthreads();

  // ---- gather: out[row] = codebook[bestk[row]], coalesced float4 ----
  const float4* cb4 = (const float4*)cb;
  float4* out4 = (float4*)out + (size_t)row0 * 16;
#pragma unroll
  for (int i = 0; i < 4; ++i) {
    int f = tid + i * NTHREADS;
    int row = f >> 4, c4 = f & 15;
    out4[f] = cb4[(size_t)bestk_s[row] * 16 + c4];
  }
}

extern "C" void kernel_launch(void* const* d_in, const int* in_sizes, int n_in,
                              void* d_out, int out_size, void* d_ws, size_t ws_size,
                              hipStream_t stream) {
  const float* x  = (const float*)d_in[0];   // [N, 64] fp32
  const float* cb = (const float*)d_in[1];   // [2048, 64] fp32
  float* out = (float*)d_out;                // [N, 64] fp32
  float* esq = (float*)d_ws;                 // [2048] fp32
  unsigned short* cbh = (unsigned short*)d_ws + 4096;  // swizzled bf16(-2e), 256 KB

  const int N = in_sizes[0] / D_DIM;         // 131072

  prep_kernel<<<(K_CB + 255) / 256, 256, 0, stream>>>(cb, esq, cbh);
  vq_mfma_kernel<<<N / BM, NTHREADS, 0, stream>>>(x, cb, esq, cbh, out);
}